// Round 2
// baseline (164.001 us; speedup 1.0000x reference)
//
#include <hip/hip_runtime.h>

// StructOnlyClassifier: per-graph node-type histogram (segment_sum over sorted
// batch ids) + tiny MLP. x (d_in[0]) is UNUSED by the reference.
//
// R2: kill global-atomic contention. Each block owns 8192 contiguous nodes,
// aggregates packed-u64 counts in an LDS histogram (64 slots relative to the
// block's first graph id; statistically spans <=~12 graphs), then drains with
// ONE global atomic per (block, graph). Threads process 32 CONTIGUOUS nodes
// each so run-length flushes are ~1 per thread.
//
// Packed u64: bits [0:16)=count(nt==0), [16:32)=count(nt==1),
//             [32:48)=count(nt==2), [48:64)=total.

constexpr int QUADS_PER_THREAD = 8;        // 8 int4 quads = 32 nodes, contiguous
constexpr int NODES_PER_BLOCK  = 256 * QUADS_PER_THREAD * 4;  // 8192
constexpr int LDS_SLOTS        = 64;

__global__ __launch_bounds__(256) void hist_kernel(
    const int* __restrict__ batch, const int* __restrict__ ntype,
    unsigned long long* __restrict__ hist, int n_quads)
{
    __shared__ unsigned long long lh[LDS_SLOTS];
    __shared__ int s_gbase;

    const int tid = threadIdx.x;
    if (tid < LDS_SLOTS) lh[tid] = 0ull;

    const long long blockBaseQ = (long long)blockIdx.x * (256 * QUADS_PER_THREAD);
    if (tid == 0) s_gbase = batch[blockBaseQ * 4];
    __syncthreads();
    const int g0 = s_gbase;

    const int4* b4 = (const int4*)batch;
    const int4* t4 = (const int4*)ntype;

    const long long baseQ = blockBaseQ + (long long)tid * QUADS_PER_THREAD;

    unsigned long long acc = 0;
    int cur = -1;

    #pragma unroll
    for (int j = 0; j < QUADS_PER_THREAD; ++j) {
        long long q = baseQ + j;
        if (q < n_quads) {
            int4 b  = b4[q];
            int4 nt = t4[q];
            int bs[4] = {b.x, b.y, b.z, b.w};
            int ts[4] = {nt.x, nt.y, nt.z, nt.w};
            #pragma unroll
            for (int k = 0; k < 4; ++k) {
                int bk = bs[k];
                if (bk != cur) {
                    if (acc) {
                        unsigned idx = (unsigned)(cur - g0);
                        if (idx < (unsigned)LDS_SLOTS) atomicAdd(&lh[idx], acc);
                        else                           atomicAdd(&hist[cur], acc);
                    }
                    cur = bk;
                    acc = 0ull;
                }
                acc += (1ull << (ts[k] * 16)) | (1ull << 48);
            }
        }
    }
    if (acc) {
        unsigned idx = (unsigned)(cur - g0);
        if (idx < (unsigned)LDS_SLOTS) atomicAdd(&lh[idx], acc);
        else                           atomicAdd(&hist[cur], acc);
    }

    __syncthreads();
    if (tid < LDS_SLOTS) {
        unsigned long long v = lh[tid];
        if (v) atomicAdd(&hist[g0 + tid], v);
    }
}

__global__ __launch_bounds__(256) void mlp_kernel(
    const unsigned long long* __restrict__ hist,
    const float* __restrict__ W1, const float* __restrict__ b1,
    const float* __restrict__ W2, const float* __restrict__ b2,
    const float* __restrict__ W3, const float* __restrict__ b3,
    float* __restrict__ out, int B)
{
    __shared__ float sW1[128], sb1[32], sW2[512], sb2[16], sW3[16], sb3[1];
    const int tid = threadIdx.x;
    for (int i = tid; i < 128; i += 256) sW1[i] = W1[i];
    for (int i = tid; i < 512; i += 256) sW2[i] = W2[i];
    if (tid < 32)  sb1[tid] = b1[tid];
    if (tid < 16)  sb2[tid] = b2[tid];
    if (tid >= 32 && tid < 48) sW3[tid - 32] = W3[tid - 32];
    if (tid == 0)  sb3[0] = b3[0];
    __syncthreads();

    const int g = blockIdx.x * blockDim.x + tid;
    if (g >= B) return;

    const unsigned long long h = hist[g];
    const float f0 = (float)(int)( h        & 0xFFFFull) - 54.5f;
    const float f1 = (float)(int)((h >> 16) & 0xFFFFull);
    const float f2 = (float)(int)((h >> 32) & 0xFFFFull);
    const float f3 = (float)(int)( h >> 48)              - 56.5f;

    float h1[32];
    #pragma unroll
    for (int j = 0; j < 32; ++j) {
        float s = sb1[j];
        s = fmaf(f0, sW1[      j], s);
        s = fmaf(f1, sW1[ 32 + j], s);
        s = fmaf(f2, sW1[ 64 + j], s);
        s = fmaf(f3, sW1[ 96 + j], s);
        h1[j] = fmaxf(0.0f, s);
    }

    float h2[16];
    #pragma unroll
    for (int m = 0; m < 16; ++m) {
        float s = sb2[m];
        #pragma unroll
        for (int j = 0; j < 32; ++j)
            s = fmaf(h1[j], sW2[j * 16 + m], s);
        h2[m] = fmaxf(0.0f, s);
    }

    float o = sb3[0];
    #pragma unroll
    for (int m = 0; m < 16; ++m)
        o = fmaf(h2[m], sW3[m], o);

    out[g] = o;
}

extern "C" void kernel_launch(void* const* d_in, const int* in_sizes, int n_in,
                              void* d_out, int out_size, void* d_ws, size_t ws_size,
                              hipStream_t stream) {
    // inputs: 0:x(N) 1:batch(N) 2:node_type(N) 3:num_graphs 4:W1 5:b1 6:W2 7:b2 8:W3 9:b3
    const int*   batch = (const int*)d_in[1];
    const int*   ntype = (const int*)d_in[2];
    const float* W1    = (const float*)d_in[4];
    const float* b1    = (const float*)d_in[5];
    const float* W2    = (const float*)d_in[6];
    const float* b2    = (const float*)d_in[7];
    const float* W3    = (const float*)d_in[8];
    const float* b3    = (const float*)d_in[9];
    float*       out   = (float*)d_out;

    const int n = in_sizes[1];          // 16,777,216 nodes
    const int B = out_size;             // 16,384 graphs

    unsigned long long* hist = (unsigned long long*)d_ws;
    hipMemsetAsync(d_ws, 0, (size_t)B * sizeof(unsigned long long), stream);

    const int n_quads = n / 4;                                  // 4,194,304
    const int blocks = (n + NODES_PER_BLOCK - 1) / NODES_PER_BLOCK;   // 2048
    hist_kernel<<<blocks, 256, 0, stream>>>(batch, ntype, hist, n_quads);

    mlp_kernel<<<(B + 255) / 256, 256, 0, stream>>>(hist, W1, b1, W2, b2, W3, b3, out, B);
}

// Round 3
// 29.705 us; speedup vs baseline: 5.5209x; 5.5209x over previous
//
#include <hip/hip_runtime.h>

// StructOnlyClassifier R3: batch is SORTED -> segment boundaries via binary
// search (kernel A), then one wave per graph reads its contiguous node_type
// segment, counts types, and computes the 4->32->16->1 MLP in-wave (kernel B).
// batch is never streamed linearly; no atomics anywhere.

__global__ __launch_bounds__(256) void bounds_kernel(
    const int* __restrict__ batch, int* __restrict__ S, int n, int nb)
{
    const int g = blockIdx.x * blockDim.x + threadIdx.x;
    if (g > nb) return;                 // g in [0, nb]
    // lower_bound: first idx with batch[idx] >= g
    int lo = 0, hi = n;
    while (lo < hi) {
        int mid = (lo + hi) >> 1;
        if (batch[mid] < g) lo = mid + 1;
        else                hi = mid;
    }
    S[g] = lo;
}

__global__ __launch_bounds__(256) void seg_mlp_kernel(
    const int* __restrict__ ntype, const int* __restrict__ S,
    const float* __restrict__ W1, const float* __restrict__ b1,
    const float* __restrict__ W2, const float* __restrict__ b2,
    const float* __restrict__ W3, const float* __restrict__ b3,
    float* __restrict__ out, int B)
{
    const int t    = blockIdx.x * blockDim.x + threadIdx.x;
    const int g    = t >> 6;            // one wave per graph
    const int lane = t & 63;
    if (g >= B) return;

    const int s   = S[g];
    const int e   = S[g + 1];
    const int len = e - s;

    int c0 = 0, c1 = 0;

    int sa = (s + 3) & ~3; if (sa > e) sa = e;   // align-up head bound
    int ea = e & ~3;       if (ea < sa) ea = sa; // align-down tail bound

    // head scalars [s, sa)
    {
        int i = s + lane;
        if (i < sa) { int v = ntype[i]; c0 += (v == 0); c1 += (v == 1); }
    }
    // main int4 quads [sa, ea), lane-contiguous per iteration
    {
        const int4* nt4 = (const int4*)ntype;
        for (int q = (sa >> 2) + lane; q < (ea >> 2); q += 64) {
            int4 v = nt4[q];
            c0 += (v.x == 0) + (v.y == 0) + (v.z == 0) + (v.w == 0);
            c1 += (v.x == 1) + (v.y == 1) + (v.z == 1) + (v.w == 1);
        }
    }
    // tail scalars [ea, e)
    {
        int i = ea + lane;
        if (i < e) { int v = ntype[i]; c0 += (v == 0); c1 += (v == 1); }
    }

    // wave reduce both counts packed in one u64
    unsigned long long p = (unsigned)c0 | ((unsigned long long)(unsigned)c1 << 32);
    #pragma unroll
    for (int off = 32; off; off >>= 1) p += __shfl_xor(p, off);
    const int c0t = (int)(p & 0xFFFFFFFFull);
    const int c1t = (int)(p >> 32);

    const float f0 = (float)c0t - 54.5f;
    const float f1 = (float)c1t;
    const float f2 = (float)(len - c0t - c1t);
    const float f3 = (float)len - 56.5f;

    // layer 1: unit j on lane (lane&31); lanes 32-63 duplicate harmlessly
    const int j = lane & 31;
    float h1 = b1[j];
    h1 = fmaf(f0, W1[      j], h1);
    h1 = fmaf(f1, W1[ 32 + j], h1);
    h1 = fmaf(f2, W1[ 64 + j], h1);
    h1 = fmaf(f3, W1[ 96 + j], h1);
    h1 = fmaxf(0.0f, h1);

    // layer 2: unit m on lane (lane&15), broadcast h1 from lanes 0..31
    const int m = lane & 15;
    float s2 = b2[m];
    #pragma unroll
    for (int jj = 0; jj < 32; ++jj) {
        float hj = __shfl(h1, jj);
        s2 = fmaf(hj, W2[jj * 16 + m], s2);
    }
    const float h2 = fmaxf(0.0f, s2);

    // layer 3: dot over 16 units via xor-reduce within 16-lane group
    float p3 = h2 * W3[m];
    p3 += __shfl_xor(p3, 8);
    p3 += __shfl_xor(p3, 4);
    p3 += __shfl_xor(p3, 2);
    p3 += __shfl_xor(p3, 1);

    if (lane == 0) out[g] = p3 + b3[0];
}

extern "C" void kernel_launch(void* const* d_in, const int* in_sizes, int n_in,
                              void* d_out, int out_size, void* d_ws, size_t ws_size,
                              hipStream_t stream) {
    // inputs: 0:x(N) 1:batch(N) 2:node_type(N) 3:num_graphs 4:W1 5:b1 6:W2 7:b2 8:W3 9:b3
    const int*   batch = (const int*)d_in[1];
    const int*   ntype = (const int*)d_in[2];
    const float* W1    = (const float*)d_in[4];
    const float* b1    = (const float*)d_in[5];
    const float* W2    = (const float*)d_in[6];
    const float* b2    = (const float*)d_in[7];
    const float* W3    = (const float*)d_in[8];
    const float* b3    = (const float*)d_in[9];
    float*       out   = (float*)d_out;

    const int n = in_sizes[1];          // 16,777,216 nodes
    const int B = out_size;             // 16,384 graphs

    int* S = (int*)d_ws;                // B+1 ints = 64 KiB+4

    bounds_kernel<<<(B + 1 + 255) / 256, 256, 0, stream>>>(batch, S, n, B);

    const int total = B * 64;           // one wave per graph
    seg_mlp_kernel<<<(total + 255) / 256, 256, 0, stream>>>(
        ntype, S, W1, b1, W2, b2, W3, b3, out, B);
}